// Round 17
// baseline (234.383 us; speedup 1.0000x reference)
//
#include <hip/hip_runtime.h>
#include <hip/hip_fp16.h>

template<int N> struct IC { static constexpr int val = N; };

// 4 halves (8B, one ds_read_b64) -> float4
__device__ __forceinline__ float4 ldh4(const void* p)
{
    uint2 u = *(const uint2*)p;
    __half2 a = *reinterpret_cast<const __half2*>(&u.x);
    __half2 b = *reinterpret_cast<const __half2*>(&u.y);
    float4 r;
    r.x = __low2float(a); r.y = __high2float(a);
    r.z = __low2float(b); r.w = __high2float(b);
    return r;
}

// ---------------------------------------------------------------------------
// Weight transpose: w[o][c][k] -> wT[(k*ci + c)*co + o].
// ---------------------------------------------------------------------------
struct WtArgs { const float* src[6]; int co[6], ci[6], k2[6], dstoff[6]; };

__global__ __launch_bounds__(256)
void transpose_weights(WtArgs a, float* __restrict__ dst0)
{
    const int L = blockIdx.x;
    const float* __restrict__ s = a.src[L];
    float* __restrict__ d = dst0 + a.dstoff[L];
    const int co = a.co[L], ci = a.ci[L], k2 = a.k2[L];
    const int n = co * ci * k2;
    for (int i = threadIdx.x; i < n; i += 256) {
        int k = i % k2;
        int c = (i / k2) % ci;
        int o = i / (k2 * ci);
        d[(k * ci + c) * co + o] = s[i];
    }
}

// ---------------------------------------------------------------------------
// Batch-invariant bilinear metadata tables: entry e = k*P+p holds
// {int4 corner-pixel-indices, float4 corner-weights} (32 B).
// ---------------------------------------------------------------------------
struct MetaArgs { const float* off[6]; int P[6], K[6], WO[6], H[6], W[6], base[6]; };

__global__ __launch_bounds__(256)
void build_meta(MetaArgs a, float* __restrict__ meta0)
{
    const int L = blockIdx.y;
    const float* __restrict__ off = a.off[L];
    const int P = a.P[L], K = a.K[L], WOv = a.WO[L], H = a.H[L], Wv = a.W[L];
    const int N = P * K * K;
    float* __restrict__ m = meta0 + (size_t)a.base[L] * 8;
    for (int e = blockIdx.x * 256 + threadIdx.x; e < N; e += gridDim.x * 256) {
        const int k = e / P, p = e - k * P;
        const int ho = p / WOv, wo = p - ho * WOv;
        const int ky = k / K, kx = k - ky * K;
        const float dy = off[(2 * k)     * P + p];
        const float dx = off[(2 * k + 1) * P + p];
        const float py = (float)(ho + ky) + dy;
        const float px = (float)(wo + kx) + dx;
        const float y0f = floorf(py), x0f = floorf(px);
        const float wy = py - y0f, wx = px - x0f;
        const int y0 = (int)y0f, x0 = (int)x0f;
        const int y1 = y0 + 1,  x1 = x0 + 1;
        const bool vy0 = ((unsigned)y0 < (unsigned)H);
        const bool vy1 = ((unsigned)y1 < (unsigned)H);
        const bool vx0 = ((unsigned)x0 < (unsigned)Wv);
        const bool vx1 = ((unsigned)x1 < (unsigned)Wv);
        const int cy0 = min(max(y0, 0), H - 1) * Wv;
        const int cy1 = min(max(y1, 0), H - 1) * Wv;
        const int cx0 = min(max(x0, 0), Wv - 1);
        const int cx1 = min(max(x1, 0), Wv - 1);
        int4 mi;
        mi.x = cy0 + cx0; mi.y = cy0 + cx1; mi.z = cy1 + cx0; mi.w = cy1 + cx1;
        float4 mw;
        mw.x = (vy0 && vx0) ? (1.f - wy) * (1.f - wx) : 0.f;
        mw.y = (vy0 && vx1) ? (1.f - wy) * wx         : 0.f;
        mw.z = (vy1 && vx0) ? wy * (1.f - wx)         : 0.f;
        mw.w = (vy1 && vx1) ? wy * wx                 : 0.f;
        *(int4*)(m + (size_t)e * 8)       = mi;
        *(float4*)(m + (size_t)e * 8 + 4) = mw;
    }
}

// ---------------------------------------------------------------------------
// Proven deformable conv kernel (round-13 behavior) + HALF:
//  HALF     : stage image in LDS as fp16 (halves LDS bytes; combine still
//             fp32 via (float)half operands). Requires CIN%4==0 path.
// ---------------------------------------------------------------------------
template<int CIN, int CINW, int COUT, int K, int H, int W, int HO, int WO,
         int S, int KSEG, int NT, int NCOMB, bool SPLITOUT, bool MET,
         int NSL = 1, int CINL = 0, int NCHS = 1, int KSPL = 1, bool HALF = false>
__global__ __launch_bounds__(NT)
void deform_lds(const float* __restrict__ x0, const float* __restrict__ x1,
                const float* __restrict__ x2, const float* __restrict__ x3,
                const float* __restrict__ off, const float* __restrict__ meta,
                const float* __restrict__ wT, const float* __restrict__ bias,
                float* __restrict__ y, size_t pstride)
{
    constexpr int K2 = K * K, HW = H * W, P = HO * WO;
    constexpr int PW = ((P + 63) / 64) * 64;
    constexpr int K2B  = (K2 + KSPL - 1) / KSPL;
    constexpr int KLEN = (K2B + KSEG - 1) / KSEG;
    constexpr int PSTR = (COUT % 2 == 0) ? COUT + 1 : COUT;
    static_assert(NT >= KSEG * PW, "NT too small for KSEG*PW");
    static_assert(!HALF || (CIN % 4 == 0 && S % 4 == 0), "HALF needs vec4 + 8B rows");

    constexpr int ELT = HALF ? 2 : 4;
    __shared__ __align__(16) unsigned char simg_raw[HW * S * ELT];
    __shared__ float part[(KSEG > 1) ? (KSEG - 1) * P * PSTR : 1];

    const int tid = threadIdx.x;
    const int b   = blockIdx.x;
    const int hy  = SPLITOUT ? blockIdx.y : 0;
    const int hch = (KSPL > 1) ? (hy % NCHS) : hy;
    const int hk  = (KSPL > 1) ? (hy / NCHS) : 0;

    const size_t xoff = (size_t)b * CINW * HW + (SPLITOUT ? (size_t)hch * CIN * HW : 0);
    const float* xb  = x0 + xoff;
    const float* xb1 = (NCOMB >= 2) ? (x1 + xoff) : nullptr;
    const float* xb2 = (NCOMB >= 3) ? (x2 + xoff) : nullptr;
    const float* xb3 = (NCOMB >= 4) ? (x3 + xoff) : nullptr;
    for (int i = tid; i < CIN * HW; i += NT) {
        int c = i / HW, hw = i - c * HW;
        bool ok = true;
        if constexpr (SPLITOUT) ok = (hch * CIN + c < CINW);
        float v = 0.f;
        if (ok) {
            v = xb[i];
            if constexpr (NCOMB >= 2) v += xb1[i];
            if constexpr (NCOMB >= 3) v += xb2[i];
            if constexpr (NCOMB >= 4) v += xb3[i];
            if constexpr (NCOMB >= 2) v = fmaxf(v, 0.f);
        }
        if constexpr (HALF) ((__half*)simg_raw)[hw * S + c] = __float2half(v);
        else                ((float*)simg_raw)[hw * S + c] = v;
    }
    __syncthreads();

    const int g  = tid / PW;
    const int p  = tid - g * PW;
    const int pc = (p < P) ? p : (P - 1);
    const bool active = (p < P);

    float acc[COUT];
#pragma unroll
    for (int o = 0; o < COUT; ++o) acc[o] = 0.f;

    if (g < KSEG) {
        if ((!SPLITOUT || hy == 0) && g == 0) {
#pragma unroll
            for (int o = 0; o < COUT; ++o) acc[o] = bias[o];
        }
        const int ho = pc / WO, wo = pc - ho * WO;
        const int kb   = hk * K2B + g * KLEN;
        const int kend = (KSPL > 1) ? min(K2, hk * K2B + K2B) : K2;

        auto run = [&](auto nc4tag) {
            constexpr int NC4 = decltype(nc4tag)::val;

            auto fma_block = [&](int i00, int i01, int i10, int i11,
                                 float w00, float w01, float w10, float w11,
                                 int kku) {
                const float* __restrict__ wk = wT + kku * (CINW * COUT)
                                             + (SPLITOUT ? hch * (CIN * COUT) : 0);
                if constexpr (HALF) {
                    const __half* __restrict__ r00 = (const __half*)simg_raw + i00 * S;
                    const __half* __restrict__ r01 = (const __half*)simg_raw + i01 * S;
                    const __half* __restrict__ r10 = (const __half*)simg_raw + i10 * S;
                    const __half* __restrict__ r11 = (const __half*)simg_raw + i11 * S;
#pragma unroll
                    for (int c4 = 0; c4 < NC4; ++c4) {
                        const float4 v00 = ldh4(r00 + c4 * 4);
                        const float4 v01 = ldh4(r01 + c4 * 4);
                        const float4 v10 = ldh4(r10 + c4 * 4);
                        const float4 v11 = ldh4(r11 + c4 * 4);
                        float4 sa;
                        sa.x = fmaf(w00, v00.x, fmaf(w01, v01.x, fmaf(w10, v10.x, w11 * v11.x)));
                        sa.y = fmaf(w00, v00.y, fmaf(w01, v01.y, fmaf(w10, v10.y, w11 * v11.y)));
                        sa.z = fmaf(w00, v00.z, fmaf(w01, v01.z, fmaf(w10, v10.z, w11 * v11.z)));
                        sa.w = fmaf(w00, v00.w, fmaf(w01, v01.w, fmaf(w10, v10.w, w11 * v11.w)));
                        const float* __restrict__ wc = wk + (c4 * 4) * COUT;
#pragma unroll
                        for (int o = 0; o < COUT; ++o) acc[o] = fmaf(wc[o], sa.x, acc[o]);
#pragma unroll
                        for (int o = 0; o < COUT; ++o) acc[o] = fmaf(wc[COUT + o], sa.y, acc[o]);
#pragma unroll
                        for (int o = 0; o < COUT; ++o) acc[o] = fmaf(wc[2 * COUT + o], sa.z, acc[o]);
#pragma unroll
                        for (int o = 0; o < COUT; ++o) acc[o] = fmaf(wc[3 * COUT + o], sa.w, acc[o]);
                    }
                } else if constexpr (CIN % 4 == 0) {
                    const float* __restrict__ r00 = (const float*)simg_raw + i00 * S;
                    const float* __restrict__ r01 = (const float*)simg_raw + i01 * S;
                    const float* __restrict__ r10 = (const float*)simg_raw + i10 * S;
                    const float* __restrict__ r11 = (const float*)simg_raw + i11 * S;
#pragma unroll
                    for (int c4 = 0; c4 < NC4; ++c4) {
                        const float4 v00 = *(const float4*)(r00 + c4 * 4);
                        const float4 v01 = *(const float4*)(r01 + c4 * 4);
                        const float4 v10 = *(const float4*)(r10 + c4 * 4);
                        const float4 v11 = *(const float4*)(r11 + c4 * 4);
                        float4 sa;
                        sa.x = fmaf(w00, v00.x, fmaf(w01, v01.x, fmaf(w10, v10.x, w11 * v11.x)));
                        sa.y = fmaf(w00, v00.y, fmaf(w01, v01.y, fmaf(w10, v10.y, w11 * v11.y)));
                        sa.z = fmaf(w00, v00.z, fmaf(w01, v01.z, fmaf(w10, v10.z, w11 * v11.z)));
                        sa.w = fmaf(w00, v00.w, fmaf(w01, v01.w, fmaf(w10, v10.w, w11 * v11.w)));
                        const float* __restrict__ wc = wk + (c4 * 4) * COUT;
#pragma unroll
                        for (int o = 0; o < COUT; ++o) acc[o] = fmaf(wc[o], sa.x, acc[o]);
#pragma unroll
                        for (int o = 0; o < COUT; ++o) acc[o] = fmaf(wc[COUT + o], sa.y, acc[o]);
#pragma unroll
                        for (int o = 0; o < COUT; ++o) acc[o] = fmaf(wc[2 * COUT + o], sa.z, acc[o]);
#pragma unroll
                        for (int o = 0; o < COUT; ++o) acc[o] = fmaf(wc[3 * COUT + o], sa.w, acc[o]);
                    }
                } else {
                    const float* __restrict__ r00 = (const float*)simg_raw + i00 * S;
                    const float* __restrict__ r01 = (const float*)simg_raw + i01 * S;
                    const float* __restrict__ r10 = (const float*)simg_raw + i10 * S;
                    const float* __restrict__ r11 = (const float*)simg_raw + i11 * S;
#pragma unroll
                    for (int c = 0; c < CIN; ++c) {
                        float sa = fmaf(w00, r00[c], fmaf(w01, r01[c],
                                   fmaf(w10, r10[c], w11 * r11[c])));
#pragma unroll
                        for (int o = 0; o < COUT; ++o)
                            acc[o] = fmaf(wk[c * COUT + o], sa, acc[o]);
                    }
                }
            };

            if constexpr (MET) {
                const int kf = (kb < K2) ? kb : (K2 - 1);
                int4   nmi = *(const int4*)  (meta + (size_t)(kf * P + pc) * 8);
                float4 nmw = *(const float4*)(meta + (size_t)(kf * P + pc) * 8 + 4);

#pragma unroll 1
                for (int j = 0; j < KLEN; ++j) {
                    const int k  = kb + j;
                    const int kk = (k < K2) ? k : (K2 - 1);
                    const int4   mi  = nmi;
                    const float4 mwv = nmw;
                    const int kn = (k + 1 < K2) ? (k + 1) : (K2 - 1);
                    nmi = *(const int4*)  (meta + (size_t)(kn * P + pc) * 8);
                    nmw = *(const float4*)(meta + (size_t)(kn * P + pc) * 8 + 4);

                    float w00 = mwv.x, w01 = mwv.y, w10 = mwv.z, w11 = mwv.w;
                    if constexpr (K2 % (KSEG * KSPL) != 0) {
                        const float kv = (k < kend) ? 1.f : 0.f;
                        w00 *= kv; w01 *= kv; w10 *= kv; w11 *= kv;
                    }
                    const int kku = __builtin_amdgcn_readfirstlane(kk);
                    fma_block(mi.x, mi.y, mi.z, mi.w, w00, w01, w10, w11, kku);
                }
            } else {
                const int kf = (kb < K2) ? kb : (K2 - 1);
                float ndy = off[(2 * kf)     * P + pc];
                float ndx = off[(2 * kf + 1) * P + pc];

#pragma unroll 1
                for (int j = 0; j < KLEN; ++j) {
                    const int k  = kb + j;
                    const int kk = (k < K2) ? k : (K2 - 1);
                    const float dy = ndy, dx = ndx;
                    const int kn = (k + 1 < K2) ? (k + 1) : (K2 - 1);
                    ndy = off[(2 * kn)     * P + pc];
                    ndx = off[(2 * kn + 1) * P + pc];

                    const int ky = kk / K, kx = kk - ky * K;
                    const float py = (float)(ho + ky) + dy;
                    const float px = (float)(wo + kx) + dx;
                    const float y0f = floorf(py), x0f = floorf(px);
                    const float wy = py - y0f, wx = px - x0f;
                    const int y0 = (int)y0f, x0 = (int)x0f;
                    const int y1 = y0 + 1,  x1i = x0 + 1;
                    const bool vy0 = ((unsigned)y0  < (unsigned)H);
                    const bool vy1 = ((unsigned)y1  < (unsigned)H);
                    const bool vx0 = ((unsigned)x0  < (unsigned)W);
                    const bool vx1 = ((unsigned)x1i < (unsigned)W);
                    const int cy0 = min(max(y0, 0), H - 1) * W;
                    const int cy1 = min(max(y1, 0), H - 1) * W;
                    const int cx0 = min(max(x0, 0), W - 1);
                    const int cx1 = min(max(x1i, 0), W - 1);
                    float w00 = (vy0 && vx0) ? (1.f - wy) * (1.f - wx) : 0.f;
                    float w01 = (vy0 && vx1) ? (1.f - wy) * wx         : 0.f;
                    float w10 = (vy1 && vx0) ? wy * (1.f - wx)         : 0.f;
                    float w11 = (vy1 && vx1) ? wy * wx                 : 0.f;
                    if constexpr (K2 % (KSEG * KSPL) != 0) {
                        const float kv = (k < kend) ? 1.f : 0.f;
                        w00 *= kv; w01 *= kv; w10 *= kv; w11 *= kv;
                    }
                    const int kku = __builtin_amdgcn_readfirstlane(kk);
                    fma_block(cy0 + cx0, cy0 + cx1, cy1 + cx0, cy1 + cx1,
                              w00, w01, w10, w11, kku);
                }
            }
        };

        if constexpr (SPLITOUT && CINL > 0) {
            if (hch == NSL - 1) run(IC<(CINL + 3) / 4>{});
            else                run(IC<(CIN + 3) / 4>{});
        } else {
            run(IC<(CIN + 3) / 4>{});
        }

        if (g > 0 && active) {
#pragma unroll
            for (int o = 0; o < COUT; ++o)
                part[(g - 1) * (P * PSTR) + p * PSTR + o] = acc[o];
        }
    }

    if constexpr (KSEG > 1) __syncthreads();

    if (g == 0 && active) {
        if constexpr (KSEG > 1) {
#pragma unroll
            for (int gg = 1; gg < KSEG; ++gg)
#pragma unroll
                for (int o = 0; o < COUT; ++o)
                    acc[o] += part[(gg - 1) * (P * PSTR) + p * PSTR + o];
        }
        float* yb = y + (SPLITOUT ? (size_t)hy * pstride : 0) + (size_t)b * COUT * P;
#pragma unroll
        for (int o = 0; o < COUT; ++o)
            yb[o * P + p] = SPLITOUT ? acc[o] : fmaxf(acc[o], 0.f);
    }
}

// ---------------------------------------------------------------------------
// Fused tail: L5 -> L6 -> perm -> FC7 -> FC8 (one block per image).
// ---------------------------------------------------------------------------
__global__ __launch_bounds__(1024)
void tail_fused(const float* __restrict__ a4p0, const float* __restrict__ a4p1,
                const float* __restrict__ meta5, const float* __restrict__ meta6,
                const float* __restrict__ wt5, const float* __restrict__ b5,
                const float* __restrict__ wt6, const float* __restrict__ b6,
                const float* __restrict__ w7, const float* __restrict__ b7,
                const float* __restrict__ w8, const float* __restrict__ b8,
                const int* __restrict__ perm, float* __restrict__ out)
{
    constexpr int HW5 = 361, P5 = 225, K25 = 25, S5 = 20;
    constexpr int HW6 = 225, P6 = 169, K26 = 9,  S6 = 12;

    __shared__ __align__(16) float simg5[HW5 * S5];
    __shared__ float part5[3 * P5 * 9];
    __shared__ __align__(16) float act5[HW6 * S6];
    __shared__ float part6[4 * P6 * 5];
    __shared__ float a6l[676];
    __shared__ float sx[676];
    __shared__ float ps[3][256];
    __shared__ float sh[256];

    const int tid = threadIdx.x;
    const int b   = blockIdx.x;

    {
        const size_t boff = (size_t)b * 16 * HW5;
        for (int i = tid; i < 16 * HW5; i += 1024) {
            int c = i / HW5, hw = i - c * HW5;
            simg5[hw * S5 + c] = fmaxf(a4p0[boff + i] + a4p1[boff + i], 0.f);
        }
    }
    __syncthreads();

    {
        const int g  = tid >> 8;
        const int p  = tid & 255;
        const int pc = (p < P5) ? p : (P5 - 1);
        const bool active = (p < P5);

        float acc[8];
#pragma unroll
        for (int o = 0; o < 8; ++o) acc[o] = (g == 0) ? b5[o] : 0.f;

        const int kb = g * 7;
        const int kf = (kb < K25) ? kb : (K25 - 1);
        int4   nmi = *(const int4*)  (meta5 + (size_t)(kf * P5 + pc) * 8);
        float4 nmw = *(const float4*)(meta5 + (size_t)(kf * P5 + pc) * 8 + 4);

#pragma unroll 1
        for (int j = 0; j < 7; ++j) {
            const int k  = kb + j;
            const int kk = (k < K25) ? k : (K25 - 1);
            const int4   mi  = nmi;
            const float4 mwv = nmw;
            const int kn = (k + 1 < K25) ? (k + 1) : (K25 - 1);
            nmi = *(const int4*)  (meta5 + (size_t)(kn * P5 + pc) * 8);
            nmw = *(const float4*)(meta5 + (size_t)(kn * P5 + pc) * 8 + 4);

            const float kv = (k < K25) ? 1.f : 0.f;
            const float w00 = mwv.x * kv, w01 = mwv.y * kv;
            const float w10 = mwv.z * kv, w11 = mwv.w * kv;
            const int kku = __builtin_amdgcn_readfirstlane(kk);
            const float* __restrict__ wk = wt5 + kku * 128;
            const float* __restrict__ r00 = simg5 + mi.x * S5;
            const float* __restrict__ r01 = simg5 + mi.y * S5;
            const float* __restrict__ r10 = simg5 + mi.z * S5;
            const float* __restrict__ r11 = simg5 + mi.w * S5;
#pragma unroll
            for (int c4 = 0; c4 < 4; ++c4) {
                const float4 v00 = *(const float4*)(r00 + c4 * 4);
                const float4 v01 = *(const float4*)(r01 + c4 * 4);
                const float4 v10 = *(const float4*)(r10 + c4 * 4);
                const float4 v11 = *(const float4*)(r11 + c4 * 4);
                float4 sa;
                sa.x = fmaf(w00, v00.x, fmaf(w01, v01.x, fmaf(w10, v10.x, w11 * v11.x)));
                sa.y = fmaf(w00, v00.y, fmaf(w01, v01.y, fmaf(w10, v10.y, w11 * v11.y)));
                sa.z = fmaf(w00, v00.z, fmaf(w01, v01.z, fmaf(w10, v10.z, w11 * v11.z)));
                sa.w = fmaf(w00, v00.w, fmaf(w01, v01.w, fmaf(w10, v10.w, w11 * v11.w)));
                const float* __restrict__ wc = wk + c4 * 32;
#pragma unroll
                for (int o = 0; o < 8; ++o) acc[o] = fmaf(wc[o],      sa.x, acc[o]);
#pragma unroll
                for (int o = 0; o < 8; ++o) acc[o] = fmaf(wc[8 + o],  sa.y, acc[o]);
#pragma unroll
                for (int o = 0; o < 8; ++o) acc[o] = fmaf(wc[16 + o], sa.z, acc[o]);
#pragma unroll
                for (int o = 0; o < 8; ++o) acc[o] = fmaf(wc[24 + o], sa.w, acc[o]);
            }
        }

        if (g > 0 && active) {
#pragma unroll
            for (int o = 0; o < 8; ++o)
                part5[(g - 1) * (P5 * 9) + p * 9 + o] = acc[o];
        }
        __syncthreads();

        if (g == 0 && active) {
#pragma unroll
            for (int gg = 1; gg < 4; ++gg)
#pragma unroll
                for (int o = 0; o < 8; ++o)
                    acc[o] += part5[(gg - 1) * (P5 * 9) + p * 9 + o];
#pragma unroll
            for (int o = 0; o < 8; ++o)
                act5[p * S6 + o] = fmaxf(acc[o], 0.f);
        }
    }
    __syncthreads();

    {
        const int g  = tid / 192;
        const int p  = tid - g * 192;
        const int pc = (p < P6) ? p : (P6 - 1);
        const bool active = (p < P6) && (g < 5);

        float acc[4];
#pragma unroll
        for (int o = 0; o < 4; ++o) acc[o] = (g == 0) ? b6[o] : 0.f;

        if (g < 5) {
            const int kb = g * 2;
            const int kf = (kb < K26) ? kb : (K26 - 1);
            int4   nmi = *(const int4*)  (meta6 + (size_t)(kf * P6 + pc) * 8);
            float4 nmw = *(const float4*)(meta6 + (size_t)(kf * P6 + pc) * 8 + 4);

#pragma unroll 1
            for (int j = 0; j < 2; ++j) {
                const int k  = kb + j;
                const int kk = (k < K26) ? k : (K26 - 1);
                const int4   mi  = nmi;
                const float4 mwv = nmw;
                const int kn = (k + 1 < K26) ? (k + 1) : (K26 - 1);
                nmi = *(const int4*)  (meta6 + (size_t)(kn * P6 + pc) * 8);
                nmw = *(const float4*)(meta6 + (size_t)(kn * P6 + pc) * 8 + 4);

                const float kv = (k < K26) ? 1.f : 0.f;
                const float w00 = mwv.x * kv, w01 = mwv.y * kv;
                const float w10 = mwv.z * kv, w11 = mwv.w * kv;
                const int kku = __builtin_amdgcn_readfirstlane(kk);
                const float* __restrict__ wk = wt6 + kku * 32;
                const float* __restrict__ r00 = act5 + mi.x * S6;
                const float* __restrict__ r01 = act5 + mi.y * S6;
                const float* __restrict__ r10 = act5 + mi.z * S6;
                const float* __restrict__ r11 = act5 + mi.w * S6;
#pragma unroll
                for (int c4 = 0; c4 < 2; ++c4) {
                    const float4 v00 = *(const float4*)(r00 + c4 * 4);
                    const float4 v01 = *(const float4*)(r01 + c4 * 4);
                    const float4 v10 = *(const float4*)(r10 + c4 * 4);
                    const float4 v11 = *(const float4*)(r11 + c4 * 4);
                    float4 sa;
                    sa.x = fmaf(w00, v00.x, fmaf(w01, v01.x, fmaf(w10, v10.x, w11 * v11.x)));
                    sa.y = fmaf(w00, v00.y, fmaf(w01, v01.y, fmaf(w10, v10.y, w11 * v11.y)));
                    sa.z = fmaf(w00, v00.z, fmaf(w01, v01.z, fmaf(w10, v10.z, w11 * v11.z)));
                    sa.w = fmaf(w00, v00.w, fmaf(w01, v01.w, fmaf(w10, v10.w, w11 * v11.w)));
                    const float* __restrict__ wc = wk + c4 * 16;
#pragma unroll
                    for (int o = 0; o < 4; ++o) acc[o] = fmaf(wc[o],      sa.x, acc[o]);
#pragma unroll
                    for (int o = 0; o < 4; ++o) acc[o] = fmaf(wc[4 + o],  sa.y, acc[o]);
#pragma unroll
                    for (int o = 0; o < 4; ++o) acc[o] = fmaf(wc[8 + o],  sa.z, acc[o]);
#pragma unroll
                    for (int o = 0; o < 4; ++o) acc[o] = fmaf(wc[12 + o], sa.w, acc[o]);
                }
            }

            if (g > 0 && active) {
#pragma unroll
                for (int o = 0; o < 4; ++o)
                    part6[(g - 1) * (P6 * 5) + p * 5 + o] = acc[o];
            }
        }
        __syncthreads();

        if (g == 0 && active) {
#pragma unroll
            for (int gg = 1; gg < 5; ++gg)
#pragma unroll
                for (int o = 0; o < 4; ++o)
                    acc[o] += part6[(gg - 1) * (P6 * 5) + p * 5 + o];
#pragma unroll
            for (int o = 0; o < 4; ++o)
                a6l[o * P6 + p] = fmaxf(acc[o], 0.f);
        }
    }
    __syncthreads();

    if (tid < 676) {
        const int c = tid / 169, pp = tid - c * 169;
        sx[tid] = a6l[c * 169 + perm[pp]];
    }
    __syncthreads();

    {
        const int j  = tid & 255;
        const int fq = tid >> 8;
        const int f0 = fq * 169;
        float a = 0.f;
#pragma unroll 4
        for (int i = 0; i < 169; ++i)
            a = fmaf(sx[f0 + i], w7[(size_t)(f0 + i) * 256 + j], a);
        if (fq > 0) ps[fq - 1][j] = a;
        __syncthreads();
        if (fq == 0)
            sh[j] = fmaxf(b7[j] + ((a + ps[0][j]) + (ps[1][j] + ps[2][j])), 0.f);
    }
    __syncthreads();

    if (tid < 10) {
        float acc8 = b8[tid];
#pragma unroll 8
        for (int jj = 0; jj < 256; ++jj)
            acc8 = fmaf(sh[jj], w8[jj * 10 + tid], acc8);
        out[(size_t)b * 10 + tid] = acc8;
    }
}

// ---------------------------------------------------------------------------
// Standalone fc head (fallback path only).
// ---------------------------------------------------------------------------
__global__ __launch_bounds__(1024)
void fc_head(const float* __restrict__ x6, const float* __restrict__ w7,
             const float* __restrict__ b7, const float* __restrict__ w8,
             const float* __restrict__ b8, const int* __restrict__ perm,
             float* __restrict__ out)
{
    constexpr int F = 676;
    __shared__ float sx[F];
    __shared__ float ps[3][256];
    __shared__ float sh[256];

    const int tid = threadIdx.x;
    const int b   = blockIdx.x;
    const int j   = tid & 255;
    const int fq  = tid >> 8;

    for (int i = tid; i < F; i += 1024) {
        int c = i / 169, p = i - c * 169;
        sx[i] = x6[(size_t)b * F + c * 169 + perm[p]];
    }
    __syncthreads();

    const int f0 = fq * 169;
    float a = 0.f;
#pragma unroll 4
    for (int i = 0; i < 169; ++i)
        a = fmaf(sx[f0 + i], w7[(size_t)(f0 + i) * 256 + j], a);

    if (fq > 0) ps[fq - 1][j] = a;
    __syncthreads();

    if (fq == 0)
        sh[j] = fmaxf(b7[j] + ((a + ps[0][j]) + (ps[1][j] + ps[2][j])), 0.f);
    __syncthreads();

    if (tid < 10) {
        float acc8 = b8[tid];
#pragma unroll 8
        for (int jj = 0; jj < 256; ++jj)
            acc8 = fmaf(sh[jj], w8[jj * 10 + tid], acc8);
        out[(size_t)b * 10 + tid] = acc8;
    }
}

// ---------------------------------------------------------------------------
extern "C" void kernel_launch(void* const* d_in, const int* in_sizes, int n_in,
                              void* d_out, int out_size, void* d_ws, size_t ws_size,
                              hipStream_t stream)
{
    const float* x    = (const float*)d_in[0];
    const float* off1 = (const float*)d_in[1];
    const float* w1   = (const float*)d_in[2];
    const float* b1   = (const float*)d_in[3];
    const float* off2 = (const float*)d_in[4];
    const float* w2   = (const float*)d_in[5];
    const float* b2   = (const float*)d_in[6];
    const float* off3 = (const float*)d_in[7];
    const float* w3   = (const float*)d_in[8];
    const float* b3   = (const float*)d_in[9];
    const float* off4 = (const float*)d_in[10];
    const float* w4   = (const float*)d_in[11];
    const float* b4   = (const float*)d_in[12];
    const float* off5 = (const float*)d_in[13];
    const float* w5   = (const float*)d_in[14];
    const float* b5   = (const float*)d_in[15];
    const float* off6 = (const float*)d_in[16];
    const float* w6   = (const float*)d_in[17];
    const float* b6   = (const float*)d_in[18];
    const float* w7   = (const float*)d_in[19];
    const float* b7   = (const float*)d_in[20];
    const float* w8   = (const float*)d_in[21];
    const float* b8   = (const float*)d_in[22];
    const int*   perm = (const int*)d_in[23];
    float* out = (float*)d_out;

    // ws layout (floats): unchanged from round 13/16.
    const int woff[6] = {0, 144, 4752, 17552, 30096, 33296};
    float* ws   = (float*)d_ws;
    float* wt   = ws;
    float* buf0 = ws + 33792;
    float* buf1 = buf0 + 3936256;

    float* a1   = buf0;
    float* a2   = buf1;
    float* p1L2 = ws + 13419520;
    float* a3   = buf0;
    float* p1L3 = ws + 10859520;
    float* a4p0 = buf1;
    float* a5   = buf0;
    float* a6   = buf1;
    float* meta = ws + 20308992;

    const int mbase[6] = {0, 8649, 16218, 31843, 49532, 55157};
    const int MTOT = 56678;

    const bool splitL3 = (ws_size >= (size_t)13419520 * sizeof(float));
    const bool splitL2 = (ws_size >= (size_t)20308992 * sizeof(float));
    const bool metaOK  = (ws_size >= (size_t)(20308992 + MTOT * 8) * sizeof(float));
    const bool split3  = (ws_size >= (size_t)24245248 * sizeof(float));
    const size_t X      = 10825728;
    const size_t pstrL2 = (size_t)(p1L2 - a2);
    const size_t pstrL4 = 1478656;

    WtArgs wa;
    wa.src[0] = w1; wa.src[1] = w2; wa.src[2] = w3;
    wa.src[3] = w4; wa.src[4] = w5; wa.src[5] = w6;
    const int cos[6] = {16, 32, 16, 16, 8, 4};
    const int cis[6] = {1, 16, 32, 16, 16, 8};
    const int k2s[6] = {9, 9, 25, 49, 25, 9};
    for (int i = 0; i < 6; ++i) {
        wa.co[i] = cos[i]; wa.ci[i] = cis[i];
        wa.k2[i] = k2s[i]; wa.dstoff[i] = woff[i];
    }
    transpose_weights<<<dim3(6), dim3(256), 0, stream>>>(wa, wt);

    const dim3 g1(256), g2(256, 2), g3(256, 3);

    if (metaOK) {
        MetaArgs ma;
        ma.off[0] = off1; ma.off[1] = off2; ma.off[2] = off3;
        ma.off[3] = off4; ma.off[4] = off5; ma.off[5] = off6;
        const int Ps[6]  = {961, 841, 625, 361, 225, 169};
        const int Ks[6]  = {3, 3, 5, 7, 5, 3};
        const int WOs[6] = {31, 29, 25, 19, 15, 13};
        const int Hs[6]  = {33, 31, 29, 25, 19, 15};
        const int Ws_[6] = {33, 31, 29, 25, 19, 15};
        for (int i = 0; i < 6; ++i) {
            ma.P[i] = Ps[i]; ma.K[i] = Ks[i]; ma.WO[i] = WOs[i];
            ma.H[i] = Hs[i]; ma.W[i] = Ws_[i]; ma.base[i] = mbase[i];
        }
        build_meta<<<dim3(64, 6), dim3(256), 0, stream>>>(ma, meta);

        deform_lds< 1,  1, 16, 3, 33, 33, 31, 31,  1, 1, 1024, 1, false, true>
            <<<g1, dim3(1024), 0, stream>>>(x, nullptr, nullptr, nullptr, off1, meta + (size_t)mbase[0]*8, wt + woff[0], b1, a1, 0);
        deform_lds< 8, 16, 32, 3, 31, 31, 29, 29, 12, 1,  896, 1, true,  true>
            <<<g2, dim3(896),  0, stream>>>(a1, nullptr, nullptr, nullptr, off2, meta + (size_t)mbase[1]*8, wt + woff[1], b2, a2, pstrL2);

        if (split3) {
            // L3 3-way ch-split {12,12,8}, fp16 LDS staging (HALF=true)
            deform_lds<12, 32, 16, 5, 29, 29, 25, 25, 12, 1,  640, 2, true,  true, 3, 8, 1, 1, true>
                <<<g3, dim3(640),  0, stream>>>(a2, p1L2, nullptr, nullptr, off3, meta + (size_t)mbase[2]*8, wt + woff[2], b3, a3, X);
            deform_lds< 8, 16, 16, 7, 25, 25, 19, 19, 12, 2,  768, 3, true,  true>
                <<<g2, dim3(768),  0, stream>>>(a3, a3 + X, a3 + 2 * X, nullptr, off4, meta + (size_t)mbase[3]*8, wt + woff[3], b4, a4p0, pstrL4);
        } else {
            deform_lds<16, 32, 16, 5, 29, 29, 25, 25, 20, 1,  640, 2, true,  true>
                <<<g2, dim3(640),  0, stream>>>(a2, p1L2, nullptr, nullptr, off3, meta + (size_t)mbase[2]*8, wt + woff[2], b3, a3, X);
            deform_lds< 8, 16, 16, 7, 25, 25, 19, 19, 12, 2,  768, 2, true,  true>
                <<<g2, dim3(768),  0, stream>>>(a3, a3 + X, nullptr, nullptr, off4, meta + (size_t)mbase[3]*8, wt + woff[3], b4, a4p0, pstrL4);
        }

        tail_fused<<<g1, dim3(1024), 0, stream>>>(
            a4p0, a4p0 + pstrL4,
            meta + (size_t)mbase[4]*8, meta + (size_t)mbase[5]*8,
            wt + woff[4], b5, wt + woff[5], b6,
            w7, b7, w8, b8, perm, out);
    } else {
        deform_lds< 1,  1, 16, 3, 33, 33, 31, 31,  1, 1, 1024, 1, false, false>
            <<<g1, dim3(1024), 0, stream>>>(x, nullptr, nullptr, nullptr, off1, nullptr, wt + woff[0], b1, a1, 0);
        if (splitL2) {
            deform_lds< 8, 16, 32, 3, 31, 31, 29, 29, 12, 1, 1024, 1, true, false>
                <<<g2, dim3(1024), 0, stream>>>(a1, nullptr, nullptr, nullptr, off2, nullptr, wt + woff[1], b2, a2, pstrL2);
        } else {
            deform_lds<16, 16, 32, 3, 31, 31, 29, 29, 20, 1, 1024, 1, false, false>
                <<<g1, dim3(1024), 0, stream>>>(a1, nullptr, nullptr, nullptr, off2, nullptr, wt + woff[1], b2, a2, 0);
        }
        if (splitL3) {
            if (splitL2) {
                deform_lds<16, 32, 16, 5, 29, 29, 25, 25, 20, 1, 1024, 2, true, false>
                    <<<g2, dim3(1024), 0, stream>>>(a2, p1L2, nullptr, nullptr, off3, nullptr, wt + woff[2], b3, a3, X);
            } else {
                deform_lds<16, 32, 16, 5, 29, 29, 25, 25, 20, 1, 1024, 1, true, false>
                    <<<g2, dim3(1024), 0, stream>>>(a2, nullptr, nullptr, nullptr, off3, nullptr, wt + woff[2], b3, a3, X);
            }
            deform_lds< 8, 16, 16, 7, 25, 25, 19, 19, 12, 2,  768, 2, true, false>
                <<<g2, dim3(768),  0, stream>>>(a3, a3 + X, nullptr, nullptr, off4, nullptr, wt + woff[3], b4, a4p0, pstrL4);
        } else {
            deform_lds<32, 32, 16, 5, 29, 29, 25, 25, 36, 1, 1024, 1, false, false>
                <<<g1, dim3(1024), 0, stream>>>(a2, nullptr, nullptr, nullptr, off3, nullptr, wt + woff[2], b3, a3, 0);
            deform_lds< 8, 16, 16, 7, 25, 25, 19, 19, 12, 2,  768, 1, true, false>
                <<<g2, dim3(768),  0, stream>>>(a3, nullptr, nullptr, nullptr, off4, nullptr, wt + woff[3], b4, a4p0, pstrL4);
        }
        deform_lds<16, 16,  8, 5, 19, 19, 15, 15, 20, 4, 1024, 2, false, false>
            <<<g1, dim3(1024), 0, stream>>>(a4p0, a4p0 + pstrL4, nullptr, nullptr, off5, nullptr, wt + woff[4], b5, a5, 0);
        deform_lds< 8,  8,  4, 3, 15, 15, 13, 13, 12, 5,  960, 1, false, false>
            <<<g1, dim3(960),  0, stream>>>(a5, nullptr, nullptr, nullptr, off6, nullptr, wt + woff[5], b6, a6, 0);
        fc_head<<<dim3(256), dim3(1024), 0, stream>>>(a6, w7, b7, w8, b8, perm, out);
    }
}

// Round 18
// 230.253 us; speedup vs baseline: 1.0179x; 1.0179x over previous
//
#include <hip/hip_runtime.h>

template<int N> struct IC { static constexpr int val = N; };

// ---------------------------------------------------------------------------
// Merged setup: blockIdx.y in [0,6): bilinear meta tables for layer y;
// blockIdx.y == 6: weight transpose w[o][c][k] -> wT[(k*ci+c)*co+o]
// (blockIdx.x selects layer, 6..63 idle).
// ---------------------------------------------------------------------------
struct SetupArgs {
    const float* wsrc[6]; int co[6], ci[6], k2[6], woff[6];
    const float* off[6];  int P[6], K[6], WO[6], H[6], W[6], mbase[6];
};

__global__ __launch_bounds__(256)
void setup_tables(SetupArgs a, float* __restrict__ wt, float* __restrict__ meta0)
{
    if (blockIdx.y == 6) {
        const int L = blockIdx.x;
        if (L >= 6) return;
        const float* __restrict__ s = a.wsrc[L];
        float* __restrict__ d = wt + a.woff[L];
        const int co = a.co[L], ci = a.ci[L], k2 = a.k2[L];
        const int n = co * ci * k2;
        for (int i = threadIdx.x; i < n; i += 256) {
            int k = i % k2;
            int c = (i / k2) % ci;
            int o = i / (k2 * ci);
            d[(k * ci + c) * co + o] = s[i];
        }
        return;
    }

    const int L = blockIdx.y;
    const float* __restrict__ off = a.off[L];
    const int P = a.P[L], K = a.K[L], WOv = a.WO[L], H = a.H[L], Wv = a.W[L];
    const int N = P * K * K;
    float* __restrict__ m = meta0 + (size_t)a.mbase[L] * 8;
    for (int e = blockIdx.x * 256 + threadIdx.x; e < N; e += gridDim.x * 256) {
        const int k = e / P, p = e - k * P;
        const int ho = p / WOv, wo = p - ho * WOv;
        const int ky = k / K, kx = k - ky * K;
        const float dy = off[(2 * k)     * P + p];
        const float dx = off[(2 * k + 1) * P + p];
        const float py = (float)(ho + ky) + dy;
        const float px = (float)(wo + kx) + dx;
        const float y0f = floorf(py), x0f = floorf(px);
        const float wy = py - y0f, wx = px - x0f;
        const int y0 = (int)y0f, x0 = (int)x0f;
        const int y1 = y0 + 1,  x1 = x0 + 1;
        const bool vy0 = ((unsigned)y0 < (unsigned)H);
        const bool vy1 = ((unsigned)y1 < (unsigned)H);
        const bool vx0 = ((unsigned)x0 < (unsigned)Wv);
        const bool vx1 = ((unsigned)x1 < (unsigned)Wv);
        const int cy0 = min(max(y0, 0), H - 1) * Wv;
        const int cy1 = min(max(y1, 0), H - 1) * Wv;
        const int cx0 = min(max(x0, 0), Wv - 1);
        const int cx1 = min(max(x1, 0), Wv - 1);
        int4 mi;
        mi.x = cy0 + cx0; mi.y = cy0 + cx1; mi.z = cy1 + cx0; mi.w = cy1 + cx1;
        float4 mw;
        mw.x = (vy0 && vx0) ? (1.f - wy) * (1.f - wx) : 0.f;
        mw.y = (vy0 && vx1) ? (1.f - wy) * wx         : 0.f;
        mw.z = (vy1 && vx0) ? wy * (1.f - wx)         : 0.f;
        mw.w = (vy1 && vx1) ? wy * wx                 : 0.f;
        *(int4*)(m + (size_t)e * 8)       = mi;
        *(float4*)(m + (size_t)e * 8 + 4) = mw;
    }
}

// Fallback-only weight transpose (no meta path).
struct WtArgs { const float* src[6]; int co[6], ci[6], k2[6], dstoff[6]; };

__global__ __launch_bounds__(256)
void transpose_weights(WtArgs a, float* __restrict__ dst0)
{
    const int L = blockIdx.x;
    const float* __restrict__ s = a.src[L];
    float* __restrict__ d = dst0 + a.dstoff[L];
    const int co = a.co[L], ci = a.ci[L], k2 = a.k2[L];
    const int n = co * ci * k2;
    for (int i = threadIdx.x; i < n; i += 256) {
        int k = i % k2;
        int c = (i / k2) % ci;
        int o = i / (k2 * ci);
        d[(k * ci + c) * co + o] = s[i];
    }
}

// ---------------------------------------------------------------------------
// Proven deformable conv kernel (round-13/16 behavior, fp32 LDS staging).
// ---------------------------------------------------------------------------
template<int CIN, int CINW, int COUT, int K, int H, int W, int HO, int WO,
         int S, int KSEG, int NT, int NCOMB, bool SPLITOUT, bool MET,
         int NSL = 1, int CINL = 0, int NCHS = 1, int KSPL = 1>
__global__ __launch_bounds__(NT)
void deform_lds(const float* __restrict__ x0, const float* __restrict__ x1,
                const float* __restrict__ x2, const float* __restrict__ x3,
                const float* __restrict__ off, const float* __restrict__ meta,
                const float* __restrict__ wT, const float* __restrict__ bias,
                float* __restrict__ y, size_t pstride)
{
    constexpr int K2 = K * K, HW = H * W, P = HO * WO;
    constexpr int PW = ((P + 63) / 64) * 64;
    constexpr int K2B  = (K2 + KSPL - 1) / KSPL;
    constexpr int KLEN = (K2B + KSEG - 1) / KSEG;
    constexpr int PSTR = (COUT % 2 == 0) ? COUT + 1 : COUT;
    static_assert(NT >= KSEG * PW, "NT too small for KSEG*PW");

    __shared__ __align__(16) float simg[HW * S];
    __shared__ float part[(KSEG > 1) ? (KSEG - 1) * P * PSTR : 1];

    const int tid = threadIdx.x;
    const int b   = blockIdx.x;
    const int hy  = SPLITOUT ? blockIdx.y : 0;
    const int hch = (KSPL > 1) ? (hy % NCHS) : hy;
    const int hk  = (KSPL > 1) ? (hy / NCHS) : 0;

    const size_t xoff = (size_t)b * CINW * HW + (SPLITOUT ? (size_t)hch * CIN * HW : 0);
    const float* xb  = x0 + xoff;
    const float* xb1 = (NCOMB >= 2) ? (x1 + xoff) : nullptr;
    const float* xb2 = (NCOMB >= 3) ? (x2 + xoff) : nullptr;
    const float* xb3 = (NCOMB >= 4) ? (x3 + xoff) : nullptr;
    for (int i = tid; i < CIN * HW; i += NT) {
        int c = i / HW, hw = i - c * HW;
        bool ok = true;
        if constexpr (SPLITOUT) ok = (hch * CIN + c < CINW);
        float v = 0.f;
        if (ok) {
            v = xb[i];
            if constexpr (NCOMB >= 2) v += xb1[i];
            if constexpr (NCOMB >= 3) v += xb2[i];
            if constexpr (NCOMB >= 4) v += xb3[i];
            if constexpr (NCOMB >= 2) v = fmaxf(v, 0.f);
        }
        simg[hw * S + c] = v;
    }
    __syncthreads();

    const int g  = tid / PW;
    const int p  = tid - g * PW;
    const int pc = (p < P) ? p : (P - 1);
    const bool active = (p < P);

    float acc[COUT];
#pragma unroll
    for (int o = 0; o < COUT; ++o) acc[o] = 0.f;

    if (g < KSEG) {
        if ((!SPLITOUT || hy == 0) && g == 0) {
#pragma unroll
            for (int o = 0; o < COUT; ++o) acc[o] = bias[o];
        }
        const int ho = pc / WO, wo = pc - ho * WO;
        const int kb   = hk * K2B + g * KLEN;
        const int kend = (KSPL > 1) ? min(K2, hk * K2B + K2B) : K2;

        auto run = [&](auto nc4tag) {
            constexpr int NC4 = decltype(nc4tag)::val;

            auto fma_block = [&](int i00, int i01, int i10, int i11,
                                 float w00, float w01, float w10, float w11,
                                 int kku) {
                const float* __restrict__ r00 = simg + i00 * S;
                const float* __restrict__ r01 = simg + i01 * S;
                const float* __restrict__ r10 = simg + i10 * S;
                const float* __restrict__ r11 = simg + i11 * S;
                const float* __restrict__ wk = wT + kku * (CINW * COUT)
                                             + (SPLITOUT ? hch * (CIN * COUT) : 0);
                if constexpr (CIN % 4 == 0) {
#pragma unroll
                    for (int c4 = 0; c4 < NC4; ++c4) {
                        const float4 v00 = *(const float4*)(r00 + c4 * 4);
                        const float4 v01 = *(const float4*)(r01 + c4 * 4);
                        const float4 v10 = *(const float4*)(r10 + c4 * 4);
                        const float4 v11 = *(const float4*)(r11 + c4 * 4);
                        float4 sa;
                        sa.x = fmaf(w00, v00.x, fmaf(w01, v01.x, fmaf(w10, v10.x, w11 * v11.x)));
                        sa.y = fmaf(w00, v00.y, fmaf(w01, v01.y, fmaf(w10, v10.y, w11 * v11.y)));
                        sa.z = fmaf(w00, v00.z, fmaf(w01, v01.z, fmaf(w10, v10.z, w11 * v11.z)));
                        sa.w = fmaf(w00, v00.w, fmaf(w01, v01.w, fmaf(w10, v10.w, w11 * v11.w)));
                        const float* __restrict__ wc = wk + (c4 * 4) * COUT;
#pragma unroll
                        for (int o = 0; o < COUT; ++o) acc[o] = fmaf(wc[o], sa.x, acc[o]);
#pragma unroll
                        for (int o = 0; o < COUT; ++o) acc[o] = fmaf(wc[COUT + o], sa.y, acc[o]);
#pragma unroll
                        for (int o = 0; o < COUT; ++o) acc[o] = fmaf(wc[2 * COUT + o], sa.z, acc[o]);
#pragma unroll
                        for (int o = 0; o < COUT; ++o) acc[o] = fmaf(wc[3 * COUT + o], sa.w, acc[o]);
                    }
                } else {
#pragma unroll
                    for (int c = 0; c < CIN; ++c) {
                        float sa = fmaf(w00, r00[c], fmaf(w01, r01[c],
                                   fmaf(w10, r10[c], w11 * r11[c])));
#pragma unroll
                        for (int o = 0; o < COUT; ++o)
                            acc[o] = fmaf(wk[c * COUT + o], sa, acc[o]);
                    }
                }
            };

            if constexpr (MET) {
                const int kf = (kb < K2) ? kb : (K2 - 1);
                int4   nmi = *(const int4*)  (meta + (size_t)(kf * P + pc) * 8);
                float4 nmw = *(const float4*)(meta + (size_t)(kf * P + pc) * 8 + 4);

#pragma unroll 1
                for (int j = 0; j < KLEN; ++j) {
                    const int k  = kb + j;
                    const int kk = (k < K2) ? k : (K2 - 1);
                    const int4   mi  = nmi;
                    const float4 mwv = nmw;
                    const int kn = (k + 1 < K2) ? (k + 1) : (K2 - 1);
                    nmi = *(const int4*)  (meta + (size_t)(kn * P + pc) * 8);
                    nmw = *(const float4*)(meta + (size_t)(kn * P + pc) * 8 + 4);

                    float w00 = mwv.x, w01 = mwv.y, w10 = mwv.z, w11 = mwv.w;
                    if constexpr (K2 % (KSEG * KSPL) != 0) {
                        const float kv = (k < kend) ? 1.f : 0.f;
                        w00 *= kv; w01 *= kv; w10 *= kv; w11 *= kv;
                    }
                    const int kku = __builtin_amdgcn_readfirstlane(kk);
                    fma_block(mi.x, mi.y, mi.z, mi.w, w00, w01, w10, w11, kku);
                }
            } else {
                const int kf = (kb < K2) ? kb : (K2 - 1);
                float ndy = off[(2 * kf)     * P + pc];
                float ndx = off[(2 * kf + 1) * P + pc];

#pragma unroll 1
                for (int j = 0; j < KLEN; ++j) {
                    const int k  = kb + j;
                    const int kk = (k < K2) ? k : (K2 - 1);
                    const float dy = ndy, dx = ndx;
                    const int kn = (k + 1 < K2) ? (k + 1) : (K2 - 1);
                    ndy = off[(2 * kn)     * P + pc];
                    ndx = off[(2 * kn + 1) * P + pc];

                    const int ky = kk / K, kx = kk - ky * K;
                    const float py = (float)(ho + ky) + dy;
                    const float px = (float)(wo + kx) + dx;
                    const float y0f = floorf(py), x0f = floorf(px);
                    const float wy = py - y0f, wx = px - x0f;
                    const int y0 = (int)y0f, x0 = (int)x0f;
                    const int y1 = y0 + 1,  x1i = x0 + 1;
                    const bool vy0 = ((unsigned)y0  < (unsigned)H);
                    const bool vy1 = ((unsigned)y1  < (unsigned)H);
                    const bool vx0 = ((unsigned)x0  < (unsigned)W);
                    const bool vx1 = ((unsigned)x1i < (unsigned)W);
                    const int cy0 = min(max(y0, 0), H - 1) * W;
                    const int cy1 = min(max(y1, 0), H - 1) * W;
                    const int cx0 = min(max(x0, 0), W - 1);
                    const int cx1 = min(max(x1i, 0), W - 1);
                    float w00 = (vy0 && vx0) ? (1.f - wy) * (1.f - wx) : 0.f;
                    float w01 = (vy0 && vx1) ? (1.f - wy) * wx         : 0.f;
                    float w10 = (vy1 && vx0) ? wy * (1.f - wx)         : 0.f;
                    float w11 = (vy1 && vx1) ? wy * wx                 : 0.f;
                    if constexpr (K2 % (KSEG * KSPL) != 0) {
                        const float kv = (k < kend) ? 1.f : 0.f;
                        w00 *= kv; w01 *= kv; w10 *= kv; w11 *= kv;
                    }
                    const int kku = __builtin_amdgcn_readfirstlane(kk);
                    fma_block(cy0 + cx0, cy0 + cx1, cy1 + cx0, cy1 + cx1,
                              w00, w01, w10, w11, kku);
                }
            }
        };

        if constexpr (SPLITOUT && CINL > 0) {
            if (hch == NSL - 1) run(IC<(CINL + 3) / 4>{});
            else                run(IC<(CIN + 3) / 4>{});
        } else {
            run(IC<(CIN + 3) / 4>{});
        }

        if (g > 0 && active) {
#pragma unroll
            for (int o = 0; o < COUT; ++o)
                part[(g - 1) * (P * PSTR) + p * PSTR + o] = acc[o];
        }
    }

    if constexpr (KSEG > 1) __syncthreads();

    if (g == 0 && active) {
        if constexpr (KSEG > 1) {
#pragma unroll
            for (int gg = 1; gg < KSEG; ++gg)
#pragma unroll
                for (int o = 0; o < COUT; ++o)
                    acc[o] += part[(gg - 1) * (P * PSTR) + p * PSTR + o];
        }
        float* yb = y + (SPLITOUT ? (size_t)hy * pstride : 0) + (size_t)b * COUT * P;
#pragma unroll
        for (int o = 0; o < COUT; ++o)
            yb[o * P + p] = SPLITOUT ? acc[o] : fmaxf(acc[o], 0.f);
    }
}

// ---------------------------------------------------------------------------
// Fused tail: L5 -> L6 -> perm -> FC7 -> FC8 (one block per image).
// ---------------------------------------------------------------------------
__global__ __launch_bounds__(1024)
void tail_fused(const float* __restrict__ a4p0, const float* __restrict__ a4p1,
                const float* __restrict__ meta5, const float* __restrict__ meta6,
                const float* __restrict__ wt5, const float* __restrict__ b5,
                const float* __restrict__ wt6, const float* __restrict__ b6,
                const float* __restrict__ w7, const float* __restrict__ b7,
                const float* __restrict__ w8, const float* __restrict__ b8,
                const int* __restrict__ perm, float* __restrict__ out)
{
    constexpr int HW5 = 361, P5 = 225, K25 = 25, S5 = 20;
    constexpr int HW6 = 225, P6 = 169, K26 = 9,  S6 = 12;

    __shared__ __align__(16) float simg5[HW5 * S5];
    __shared__ float part5[3 * P5 * 9];
    __shared__ __align__(16) float act5[HW6 * S6];
    __shared__ float part6[4 * P6 * 5];
    __shared__ float a6l[676];
    __shared__ float sx[676];
    __shared__ float ps[3][256];
    __shared__ float sh[256];

    const int tid = threadIdx.x;
    const int b   = blockIdx.x;

    {
        const size_t boff = (size_t)b * 16 * HW5;
        for (int i = tid; i < 16 * HW5; i += 1024) {
            int c = i / HW5, hw = i - c * HW5;
            simg5[hw * S5 + c] = fmaxf(a4p0[boff + i] + a4p1[boff + i], 0.f);
        }
    }
    __syncthreads();

    {
        const int g  = tid >> 8;
        const int p  = tid & 255;
        const int pc = (p < P5) ? p : (P5 - 1);
        const bool active = (p < P5);

        float acc[8];
#pragma unroll
        for (int o = 0; o < 8; ++o) acc[o] = (g == 0) ? b5[o] : 0.f;

        const int kb = g * 7;
        const int kf = (kb < K25) ? kb : (K25 - 1);
        int4   nmi = *(const int4*)  (meta5 + (size_t)(kf * P5 + pc) * 8);
        float4 nmw = *(const float4*)(meta5 + (size_t)(kf * P5 + pc) * 8 + 4);

#pragma unroll 1
        for (int j = 0; j < 7; ++j) {
            const int k  = kb + j;
            const int kk = (k < K25) ? k : (K25 - 1);
            const int4   mi  = nmi;
            const float4 mwv = nmw;
            const int kn = (k + 1 < K25) ? (k + 1) : (K25 - 1);
            nmi = *(const int4*)  (meta5 + (size_t)(kn * P5 + pc) * 8);
            nmw = *(const float4*)(meta5 + (size_t)(kn * P5 + pc) * 8 + 4);

            const float kv = (k < K25) ? 1.f : 0.f;
            const float w00 = mwv.x * kv, w01 = mwv.y * kv;
            const float w10 = mwv.z * kv, w11 = mwv.w * kv;
            const int kku = __builtin_amdgcn_readfirstlane(kk);
            const float* __restrict__ wk = wt5 + kku * 128;
            const float* __restrict__ r00 = simg5 + mi.x * S5;
            const float* __restrict__ r01 = simg5 + mi.y * S5;
            const float* __restrict__ r10 = simg5 + mi.z * S5;
            const float* __restrict__ r11 = simg5 + mi.w * S5;
#pragma unroll
            for (int c4 = 0; c4 < 4; ++c4) {
                const float4 v00 = *(const float4*)(r00 + c4 * 4);
                const float4 v01 = *(const float4*)(r01 + c4 * 4);
                const float4 v10 = *(const float4*)(r10 + c4 * 4);
                const float4 v11 = *(const float4*)(r11 + c4 * 4);
                float4 sa;
                sa.x = fmaf(w00, v00.x, fmaf(w01, v01.x, fmaf(w10, v10.x, w11 * v11.x)));
                sa.y = fmaf(w00, v00.y, fmaf(w01, v01.y, fmaf(w10, v10.y, w11 * v11.y)));
                sa.z = fmaf(w00, v00.z, fmaf(w01, v01.z, fmaf(w10, v10.z, w11 * v11.z)));
                sa.w = fmaf(w00, v00.w, fmaf(w01, v01.w, fmaf(w10, v10.w, w11 * v11.w)));
                const float* __restrict__ wc = wk + c4 * 32;
#pragma unroll
                for (int o = 0; o < 8; ++o) acc[o] = fmaf(wc[o],      sa.x, acc[o]);
#pragma unroll
                for (int o = 0; o < 8; ++o) acc[o] = fmaf(wc[8 + o],  sa.y, acc[o]);
#pragma unroll
                for (int o = 0; o < 8; ++o) acc[o] = fmaf(wc[16 + o], sa.z, acc[o]);
#pragma unroll
                for (int o = 0; o < 8; ++o) acc[o] = fmaf(wc[24 + o], sa.w, acc[o]);
            }
        }

        if (g > 0 && active) {
#pragma unroll
            for (int o = 0; o < 8; ++o)
                part5[(g - 1) * (P5 * 9) + p * 9 + o] = acc[o];
        }
        __syncthreads();

        if (g == 0 && active) {
#pragma unroll
            for (int gg = 1; gg < 4; ++gg)
#pragma unroll
                for (int o = 0; o < 8; ++o)
                    acc[o] += part5[(gg - 1) * (P5 * 9) + p * 9 + o];
#pragma unroll
            for (int o = 0; o < 8; ++o)
                act5[p * S6 + o] = fmaxf(acc[o], 0.f);
        }
    }
    __syncthreads();

    {
        const int g  = tid / 192;
        const int p  = tid - g * 192;
        const int pc = (p < P6) ? p : (P6 - 1);
        const bool active = (p < P6) && (g < 5);

        float acc[4];
#pragma unroll
        for (int o = 0; o < 4; ++o) acc[o] = (g == 0) ? b6[o] : 0.f;

        if (g < 5) {
            const int kb = g * 2;
            const int kf = (kb < K26) ? kb : (K26 - 1);
            int4   nmi = *(const int4*)  (meta6 + (size_t)(kf * P6 + pc) * 8);
            float4 nmw = *(const float4*)(meta6 + (size_t)(kf * P6 + pc) * 8 + 4);

#pragma unroll 1
            for (int j = 0; j < 2; ++j) {
                const int k  = kb + j;
                const int kk = (k < K26) ? k : (K26 - 1);
                const int4   mi  = nmi;
                const float4 mwv = nmw;
                const int kn = (k + 1 < K26) ? (k + 1) : (K26 - 1);
                nmi = *(const int4*)  (meta6 + (size_t)(kn * P6 + pc) * 8);
                nmw = *(const float4*)(meta6 + (size_t)(kn * P6 + pc) * 8 + 4);

                const float kv = (k < K26) ? 1.f : 0.f;
                const float w00 = mwv.x * kv, w01 = mwv.y * kv;
                const float w10 = mwv.z * kv, w11 = mwv.w * kv;
                const int kku = __builtin_amdgcn_readfirstlane(kk);
                const float* __restrict__ wk = wt6 + kku * 32;
                const float* __restrict__ r00 = act5 + mi.x * S6;
                const float* __restrict__ r01 = act5 + mi.y * S6;
                const float* __restrict__ r10 = act5 + mi.z * S6;
                const float* __restrict__ r11 = act5 + mi.w * S6;
#pragma unroll
                for (int c4 = 0; c4 < 2; ++c4) {
                    const float4 v00 = *(const float4*)(r00 + c4 * 4);
                    const float4 v01 = *(const float4*)(r01 + c4 * 4);
                    const float4 v10 = *(const float4*)(r10 + c4 * 4);
                    const float4 v11 = *(const float4*)(r11 + c4 * 4);
                    float4 sa;
                    sa.x = fmaf(w00, v00.x, fmaf(w01, v01.x, fmaf(w10, v10.x, w11 * v11.x)));
                    sa.y = fmaf(w00, v00.y, fmaf(w01, v01.y, fmaf(w10, v10.y, w11 * v11.y)));
                    sa.z = fmaf(w00, v00.z, fmaf(w01, v01.z, fmaf(w10, v10.z, w11 * v11.z)));
                    sa.w = fmaf(w00, v00.w, fmaf(w01, v01.w, fmaf(w10, v10.w, w11 * v11.w)));
                    const float* __restrict__ wc = wk + c4 * 16;
#pragma unroll
                    for (int o = 0; o < 4; ++o) acc[o] = fmaf(wc[o],      sa.x, acc[o]);
#pragma unroll
                    for (int o = 0; o < 4; ++o) acc[o] = fmaf(wc[4 + o],  sa.y, acc[o]);
#pragma unroll
                    for (int o = 0; o < 4; ++o) acc[o] = fmaf(wc[8 + o],  sa.z, acc[o]);
#pragma unroll
                    for (int o = 0; o < 4; ++o) acc[o] = fmaf(wc[12 + o], sa.w, acc[o]);
                }
            }

            if (g > 0 && active) {
#pragma unroll
                for (int o = 0; o < 4; ++o)
                    part6[(g - 1) * (P6 * 5) + p * 5 + o] = acc[o];
            }
        }
        __syncthreads();

        if (g == 0 && active) {
#pragma unroll
            for (int gg = 1; gg < 5; ++gg)
#pragma unroll
                for (int o = 0; o < 4; ++o)
                    acc[o] += part6[(gg - 1) * (P6 * 5) + p * 5 + o];
#pragma unroll
            for (int o = 0; o < 4; ++o)
                a6l[o * P6 + p] = fmaxf(acc[o], 0.f);
        }
    }
    __syncthreads();

    if (tid < 676) {
        const int c = tid / 169, pp = tid - c * 169;
        sx[tid] = a6l[c * 169 + perm[pp]];
    }
    __syncthreads();

    {
        const int j  = tid & 255;
        const int fq = tid >> 8;
        const int f0 = fq * 169;
        float a = 0.f;
#pragma unroll 4
        for (int i = 0; i < 169; ++i)
            a = fmaf(sx[f0 + i], w7[(size_t)(f0 + i) * 256 + j], a);
        if (fq > 0) ps[fq - 1][j] = a;
        __syncthreads();
        if (fq == 0)
            sh[j] = fmaxf(b7[j] + ((a + ps[0][j]) + (ps[1][j] + ps[2][j])), 0.f);
    }
    __syncthreads();

    if (tid < 10) {
        float acc8 = b8[tid];
#pragma unroll 8
        for (int jj = 0; jj < 256; ++jj)
            acc8 = fmaf(sh[jj], w8[jj * 10 + tid], acc8);
        out[(size_t)b * 10 + tid] = acc8;
    }
}

// ---------------------------------------------------------------------------
// Standalone fc head (fallback path only).
// ---------------------------------------------------------------------------
__global__ __launch_bounds__(1024)
void fc_head(const float* __restrict__ x6, const float* __restrict__ w7,
             const float* __restrict__ b7, const float* __restrict__ w8,
             const float* __restrict__ b8, const int* __restrict__ perm,
             float* __restrict__ out)
{
    constexpr int F = 676;
    __shared__ float sx[F];
    __shared__ float ps[3][256];
    __shared__ float sh[256];

    const int tid = threadIdx.x;
    const int b   = blockIdx.x;
    const int j   = tid & 255;
    const int fq  = tid >> 8;

    for (int i = tid; i < F; i += 1024) {
        int c = i / 169, p = i - c * 169;
        sx[i] = x6[(size_t)b * F + c * 169 + perm[p]];
    }
    __syncthreads();

    const int f0 = fq * 169;
    float a = 0.f;
#pragma unroll 4
    for (int i = 0; i < 169; ++i)
        a = fmaf(sx[f0 + i], w7[(size_t)(f0 + i) * 256 + j], a);

    if (fq > 0) ps[fq - 1][j] = a;
    __syncthreads();

    if (fq == 0)
        sh[j] = fmaxf(b7[j] + ((a + ps[0][j]) + (ps[1][j] + ps[2][j])), 0.f);
    __syncthreads();

    if (tid < 10) {
        float acc8 = b8[tid];
#pragma unroll 8
        for (int jj = 0; jj < 256; ++jj)
            acc8 = fmaf(sh[jj], w8[jj * 10 + tid], acc8);
        out[(size_t)b * 10 + tid] = acc8;
    }
}

// ---------------------------------------------------------------------------
extern "C" void kernel_launch(void* const* d_in, const int* in_sizes, int n_in,
                              void* d_out, int out_size, void* d_ws, size_t ws_size,
                              hipStream_t stream)
{
    const float* x    = (const float*)d_in[0];
    const float* off1 = (const float*)d_in[1];
    const float* w1   = (const float*)d_in[2];
    const float* b1   = (const float*)d_in[3];
    const float* off2 = (const float*)d_in[4];
    const float* w2   = (const float*)d_in[5];
    const float* b2   = (const float*)d_in[6];
    const float* off3 = (const float*)d_in[7];
    const float* w3   = (const float*)d_in[8];
    const float* b3   = (const float*)d_in[9];
    const float* off4 = (const float*)d_in[10];
    const float* w4   = (const float*)d_in[11];
    const float* b4   = (const float*)d_in[12];
    const float* off5 = (const float*)d_in[13];
    const float* w5   = (const float*)d_in[14];
    const float* b5   = (const float*)d_in[15];
    const float* off6 = (const float*)d_in[16];
    const float* w6   = (const float*)d_in[17];
    const float* b6   = (const float*)d_in[18];
    const float* w7   = (const float*)d_in[19];
    const float* b7   = (const float*)d_in[20];
    const float* w8   = (const float*)d_in[21];
    const float* b8   = (const float*)d_in[22];
    const int*   perm = (const int*)d_in[23];
    float* out = (float*)d_out;

    // ws layout (floats): unchanged from rounds 13-16.
    const int woff[6] = {0, 144, 4752, 17552, 30096, 33296};
    float* ws   = (float*)d_ws;
    float* wt   = ws;
    float* buf0 = ws + 33792;
    float* buf1 = buf0 + 3936256;

    float* a1   = buf0;
    float* a2   = buf1;
    float* p1L2 = ws + 13419520;
    float* a3   = buf0;
    float* p1L3 = ws + 10859520;
    float* a4p0 = buf1;
    float* a5   = buf0;
    float* a6   = buf1;
    float* meta = ws + 20308992;

    const int mbase[6] = {0, 8649, 16218, 31843, 49532, 55157};
    const int MTOT = 56678;

    const bool splitL3 = (ws_size >= (size_t)13419520 * sizeof(float));
    const bool splitL2 = (ws_size >= (size_t)20308992 * sizeof(float));
    const bool metaOK  = (ws_size >= (size_t)(20308992 + MTOT * 8) * sizeof(float));
    const bool split3  = (ws_size >= (size_t)24245248 * sizeof(float));
    const size_t X      = 10825728;
    const size_t pstrL2 = (size_t)(p1L2 - a2);
    const size_t pstrL4 = 1478656;

    const int cos[6] = {16, 32, 16, 16, 8, 4};
    const int cis[6] = {1, 16, 32, 16, 16, 8};
    const int k2s[6] = {9, 9, 25, 49, 25, 9};

    const dim3 g1(256), g2(256, 2), g3(256, 3);

    if (metaOK) {
        SetupArgs sa;
        sa.wsrc[0] = w1; sa.wsrc[1] = w2; sa.wsrc[2] = w3;
        sa.wsrc[3] = w4; sa.wsrc[4] = w5; sa.wsrc[5] = w6;
        sa.off[0] = off1; sa.off[1] = off2; sa.off[2] = off3;
        sa.off[3] = off4; sa.off[4] = off5; sa.off[5] = off6;
        const int Ps[6]  = {961, 841, 625, 361, 225, 169};
        const int Ks[6]  = {3, 3, 5, 7, 5, 3};
        const int WOs[6] = {31, 29, 25, 19, 15, 13};
        const int Hs[6]  = {33, 31, 29, 25, 19, 15};
        for (int i = 0; i < 6; ++i) {
            sa.co[i] = cos[i]; sa.ci[i] = cis[i]; sa.k2[i] = k2s[i];
            sa.woff[i] = woff[i];
            sa.P[i] = Ps[i]; sa.K[i] = Ks[i]; sa.WO[i] = WOs[i];
            sa.H[i] = Hs[i]; sa.W[i] = Hs[i]; sa.mbase[i] = mbase[i];
        }
        setup_tables<<<dim3(64, 7), dim3(256), 0, stream>>>(sa, wt, meta);

        deform_lds< 1,  1, 16, 3, 33, 33, 31, 31,  1, 1, 1024, 1, false, true>
            <<<g1, dim3(1024), 0, stream>>>(x, nullptr, nullptr, nullptr, off1, meta + (size_t)mbase[0]*8, wt + woff[0], b1, a1, 0);
        deform_lds< 8, 16, 32, 3, 31, 31, 29, 29, 12, 1,  896, 1, true,  true>
            <<<g2, dim3(896),  0, stream>>>(a1, nullptr, nullptr, nullptr, off2, meta + (size_t)mbase[1]*8, wt + woff[1], b2, a2, pstrL2);

        if (split3) {
            deform_lds<12, 32, 16, 5, 29, 29, 25, 25, 12, 1,  640, 2, true,  true, 3, 8>
                <<<g3, dim3(640),  0, stream>>>(a2, p1L2, nullptr, nullptr, off3, meta + (size_t)mbase[2]*8, wt + woff[2], b3, a3, X);
            deform_lds< 8, 16, 16, 7, 25, 25, 19, 19, 12, 2,  768, 3, true,  true>
                <<<g2, dim3(768),  0, stream>>>(a3, a3 + X, a3 + 2 * X, nullptr, off4, meta + (size_t)mbase[3]*8, wt + woff[3], b4, a4p0, pstrL4);
        } else {
            deform_lds<16, 32, 16, 5, 29, 29, 25, 25, 20, 1,  640, 2, true,  true>
                <<<g2, dim3(640),  0, stream>>>(a2, p1L2, nullptr, nullptr, off3, meta + (size_t)mbase[2]*8, wt + woff[2], b3, a3, X);
            deform_lds< 8, 16, 16, 7, 25, 25, 19, 19, 12, 2,  768, 2, true,  true>
                <<<g2, dim3(768),  0, stream>>>(a3, a3 + X, nullptr, nullptr, off4, meta + (size_t)mbase[3]*8, wt + woff[3], b4, a4p0, pstrL4);
        }

        tail_fused<<<g1, dim3(1024), 0, stream>>>(
            a4p0, a4p0 + pstrL4,
            meta + (size_t)mbase[4]*8, meta + (size_t)mbase[5]*8,
            wt + woff[4], b5, wt + woff[5], b6,
            w7, b7, w8, b8, perm, out);
    } else {
        WtArgs wa;
        wa.src[0] = w1; wa.src[1] = w2; wa.src[2] = w3;
        wa.src[3] = w4; wa.src[4] = w5; wa.src[5] = w6;
        for (int i = 0; i < 6; ++i) {
            wa.co[i] = cos[i]; wa.ci[i] = cis[i];
            wa.k2[i] = k2s[i]; wa.dstoff[i] = woff[i];
        }
        transpose_weights<<<dim3(6), dim3(256), 0, stream>>>(wa, wt);

        deform_lds< 1,  1, 16, 3, 33, 33, 31, 31,  1, 1, 1024, 1, false, false>
            <<<g1, dim3(1024), 0, stream>>>(x, nullptr, nullptr, nullptr, off1, nullptr, wt + woff[0], b1, a1, 0);
        if (splitL2) {
            deform_lds< 8, 16, 32, 3, 31, 31, 29, 29, 12, 1, 1024, 1, true, false>
                <<<g2, dim3(1024), 0, stream>>>(a1, nullptr, nullptr, nullptr, off2, nullptr, wt + woff[1], b2, a2, pstrL2);
        } else {
            deform_lds<16, 16, 32, 3, 31, 31, 29, 29, 20, 1, 1024, 1, false, false>
                <<<g1, dim3(1024), 0, stream>>>(a1, nullptr, nullptr, nullptr, off2, nullptr, wt + woff[1], b2, a2, 0);
        }
        if (splitL3) {
            if (splitL2) {
                deform_lds<16, 32, 16, 5, 29, 29, 25, 25, 20, 1, 1024, 2, true, false>
                    <<<g2, dim3(1024), 0, stream>>>(a2, p1L2, nullptr, nullptr, off3, nullptr, wt + woff[2], b3, a3, X);
            } else {
                deform_lds<16, 32, 16, 5, 29, 29, 25, 25, 20, 1, 1024, 1, true, false>
                    <<<g2, dim3(1024), 0, stream>>>(a2, nullptr, nullptr, nullptr, off3, nullptr, wt + woff[2], b3, a3, X);
            }
            deform_lds< 8, 16, 16, 7, 25, 25, 19, 19, 12, 2,  768, 2, true, false>
                <<<g2, dim3(768),  0, stream>>>(a3, a3 + X, nullptr, nullptr, off4, nullptr, wt + woff[3], b4, a4p0, pstrL4);
        } else {
            deform_lds<32, 32, 16, 5, 29, 29, 25, 25, 36, 1, 1024, 1, false, false>
                <<<g1, dim3(1024), 0, stream>>>(a2, nullptr, nullptr, nullptr, off3, nullptr, wt + woff[2], b3, a3, 0);
            deform_lds< 8, 16, 16, 7, 25, 25, 19, 19, 12, 2,  768, 1, true, false>
                <<<g2, dim3(768),  0, stream>>>(a3, nullptr, nullptr, nullptr, off4, nullptr, wt + woff[3], b4, a4p0, pstrL4);
        }
        deform_lds<16, 16,  8, 5, 19, 19, 15, 15, 20, 4, 1024, 2, false, false>
            <<<g1, dim3(1024), 0, stream>>>(a4p0, a4p0 + pstrL4, nullptr, nullptr, off5, nullptr, wt + woff[4], b5, a5, 0);
        deform_lds< 8,  8,  4, 3, 15, 15, 13, 13, 12, 5,  960, 1, false, false>
            <<<g1, dim3(960),  0, stream>>>(a5, nullptr, nullptr, nullptr, off6, nullptr, wt + woff[5], b6, a6, 0);
        fc_head<<<dim3(256), dim3(1024), 0, stream>>>(a6, w7, b7, w8, b8, perm, out);
    }
}